// Round 1
// baseline (34.459 us; speedup 1.0000x reference)
//
#include <hip/hip_runtime.h>

// MaxUnpool2D: in [16,64,64,128] f32, mask [16,64,64,128] i32 (flat NHWC index
// with Ho=128, Wo=128, guaranteed inside the 2x2 window of each input elem),
// out [16,128,128,128] f32.
//
// No scatter collisions (windows partition the output; channel preserved), so
// each thread owns one input float4 and writes the full 2x2 window for its 4
// channels: selected slot = value, others = 0. Single pass, output fully
// initialized every call (harness poisons d_out with 0xAA once).

__global__ __launch_bounds__(256) void MaxUnpool2D_59047210385945_kernel(
    const float4* __restrict__ in, const int4* __restrict__ mask,
    float4* __restrict__ out, int n4) {
    int i = blockIdx.x * blockDim.x + threadIdx.x;
    if (i >= n4) return;

    // i indexes float4 groups: c4 = i & 31 (C/4 = 32), w = (i>>5)&63,
    // h = (i>>11)&63, b = i>>17.
    int c4 = i & 31;
    int w  = (i >> 5) & 63;
    int h  = (i >> 11) & 63;
    int b  = i >> 17;

    float4 v = in[i];
    int4   m = mask[i];

    float4 o00, o01, o10, o11;

    // Per-channel slot decode: dh = bit14 of mask, dw = bit7 of mask.
    {
        int dh = (m.x >> 14) & 1, dw = (m.x >> 7) & 1;
        o00.x = (dh == 0 && dw == 0) ? v.x : 0.0f;
        o01.x = (dh == 0 && dw == 1) ? v.x : 0.0f;
        o10.x = (dh == 1 && dw == 0) ? v.x : 0.0f;
        o11.x = (dh == 1 && dw == 1) ? v.x : 0.0f;
    }
    {
        int dh = (m.y >> 14) & 1, dw = (m.y >> 7) & 1;
        o00.y = (dh == 0 && dw == 0) ? v.y : 0.0f;
        o01.y = (dh == 0 && dw == 1) ? v.y : 0.0f;
        o10.y = (dh == 1 && dw == 0) ? v.y : 0.0f;
        o11.y = (dh == 1 && dw == 1) ? v.y : 0.0f;
    }
    {
        int dh = (m.z >> 14) & 1, dw = (m.z >> 7) & 1;
        o00.z = (dh == 0 && dw == 0) ? v.z : 0.0f;
        o01.z = (dh == 0 && dw == 1) ? v.z : 0.0f;
        o10.z = (dh == 1 && dw == 0) ? v.z : 0.0f;
        o11.z = (dh == 1 && dw == 1) ? v.z : 0.0f;
    }
    {
        int dh = (m.w >> 14) & 1, dw = (m.w >> 7) & 1;
        o00.w = (dh == 0 && dw == 0) ? v.w : 0.0f;
        o01.w = (dh == 0 && dw == 1) ? v.w : 0.0f;
        o10.w = (dh == 1 && dw == 0) ? v.w : 0.0f;
        o11.w = (dh == 1 && dw == 1) ? v.w : 0.0f;
    }

    // Output base in float4 units: ((b*128 + 2h)*128 + 2w)*128 floats + c4*4
    // -> /4: (((b*128 + 2h)*128 + 2w) << 5) + c4.
    int base = ((((b << 7) + 2 * h) << 7) + 2 * w);
    base = (base << 5) + c4;

    out[base]             = o00;   // (2h,   2w  )
    out[base + 32]        = o01;   // (2h,   2w+1)  +C floats
    out[base + 4096]      = o10;   // (2h+1, 2w  )  +Wo*C floats
    out[base + 4096 + 32] = o11;   // (2h+1, 2w+1)
}

extern "C" void kernel_launch(void* const* d_in, const int* in_sizes, int n_in,
                              void* d_out, int out_size, void* d_ws, size_t ws_size,
                              hipStream_t stream) {
    const float4* in   = (const float4*)d_in[0];
    const int4*   mask = (const int4*)d_in[1];
    float4*       out  = (float4*)d_out;

    int n4 = in_sizes[0] / 4;  // 16*64*64*128 / 4 = 2,097,152
    int threads = 256;
    int blocks = (n4 + threads - 1) / threads;
    MaxUnpool2D_59047210385945_kernel<<<blocks, threads, 0, stream>>>(in, mask, out, n4);
}